// Round 7
// baseline (784.242 us; speedup 1.0000x reference)
//
#include <hip/hip_runtime.h>
#include <hip/hip_bf16.h>

// Problem constants (shapes fixed by the reference; N/E derived at launch).
#define IN_DIM 256
#define OUT_DIM 128
#define SLOPE 0.1f

typedef __attribute__((ext_vector_type(8))) _Float16 f16x8;
typedef __attribute__((ext_vector_type(4))) float f32x4;
typedef __attribute__((ext_vector_type(8))) unsigned short u16x8;

// ---------------------------------------------------------------------------
// W convert: fp32 [128][256] -> f16 [128][256] row-major (K-contiguous).
// ---------------------------------------------------------------------------
__global__ void convert_w_kernel(const float* __restrict__ W,
                                 _Float16* __restrict__ Wf, int total) {
  int i = blockIdx.x * blockDim.x + threadIdx.x;
  if (i < total) Wf[i] = (_Float16)W[i];
}

// ---------------------------------------------------------------------------
// Split-f16 MFMA GEMM: emb[N][128] = A[N][256] @ W^T + b.
// A = Ahi + Alo (f16 pair); W single f16; 2 MFMA per tile, fp32 accumulate.
// Whole Wf (64 KB) staged to LDS once per block with XOR swizzle
// (byte ^= (row&7)<<4) so per-column fragment reads are ~2-way conflicts.
// Epilogue fuses bias + a1/a2 attention dots.
// ---------------------------------------------------------------------------
__global__ __launch_bounds__(256) void gemm_mfma_kernel(
    const float* __restrict__ A,      // [N][256]
    const _Float16* __restrict__ Wf,  // [128][256]
    const float* __restrict__ bias,   // [128]
    const float* __restrict__ avec,   // [256]
    float* __restrict__ emb,          // [N][128]
    float* __restrict__ a1,           // [N]
    float* __restrict__ a2,           // [N]
    int N) {
  __shared__ _Float16 wlds[32768];    // 64 KB

  const int tid = threadIdx.x;

#pragma unroll
  for (int i = 0; i < 16; ++i) {
    int chunk = tid + i * 256;        // 4096 chunks of 16B
    int f = chunk << 4;
    int n = f >> 9;
    int o = f & 511;
    int osrc = o ^ ((n & 7) << 4);
    u16x8 v = *(const u16x8*)((const char*)Wf + (size_t)n * 512 + osrc);
    *(u16x8*)((char*)wlds + f) = v;
  }
  __syncthreads();

  const int lane = tid & 63;
  const int wave = tid >> 6;
  const int m0 = blockIdx.x * 64 + wave * 16;
  const int lr = lane & 15;  // A-row / B-col / C-col within tile
  const int kg = lane >> 4;  // k-group (A/B), row-group (C)

  int arow = m0 + lr;
  if (arow > N - 1) arow = N - 1;  // clamp: loads valid, stores guarded
  const float* aptr = A + (size_t)arow * IN_DIM + kg * 8;

  f32x4 acc[8];
#pragma unroll
  for (int t = 0; t < 8; ++t) acc[t] = (f32x4)(0.f);

  const int rowbase = lr * 512;
  const int swzmask = (lr & 7) << 4;

  for (int k0 = 0; k0 < IN_DIM; k0 += 32) {
    float4 q0 = *(const float4*)(aptr + k0);
    float4 q1 = *(const float4*)(aptr + k0 + 4);
    float qs[8] = {q0.x, q0.y, q0.z, q0.w, q1.x, q1.y, q1.z, q1.w};
    f16x8 ahi, alo;
#pragma unroll
    for (int j = 0; j < 8; ++j) {
      float x = qs[j];
      _Float16 h = (_Float16)x;
      ahi[j] = h;
      alo[j] = (_Float16)(x - (float)h);
    }
    const int ko = ((k0 * 2 + kg * 16) ^ swzmask);
    const char* wl = (const char*)wlds + rowbase + ko;
#pragma unroll
    for (int t = 0; t < 8; ++t) {
      f16x8 bf = *(const f16x8*)(wl + t * 8192);
      acc[t] = __builtin_amdgcn_mfma_f32_16x16x32_f16(ahi, bf, acc[t], 0, 0, 0);
      acc[t] = __builtin_amdgcn_mfma_f32_16x16x32_f16(alo, bf, acc[t], 0, 0, 0);
    }
  }

  // Epilogue. C/D layout (m89-verified): col = lane&15, row = (lane>>4)*4+v.
  float p1[4] = {0.f, 0.f, 0.f, 0.f};
  float p2[4] = {0.f, 0.f, 0.f, 0.f};
#pragma unroll
  for (int t = 0; t < 8; ++t) {
    const int c = t * 16 + lr;
    const float bv = bias[c];
    const float av1 = avec[c];
    const float av2 = avec[OUT_DIM + c];
#pragma unroll
    for (int v = 0; v < 4; ++v) {
      const int r = m0 + kg * 4 + v;
      const float e = acc[t][v] + bv;
      if (r < N) emb[(size_t)r * OUT_DIM + c] = e;
      p1[v] += e * av1;
      p2[v] += e * av2;
    }
  }
#pragma unroll
  for (int v = 0; v < 4; ++v) {
#pragma unroll
    for (int d = 1; d < 16; d <<= 1) {
      p1[v] += __shfl_xor(p1[v], d, 64);
      p2[v] += __shfl_xor(p2[v], d, 64);
    }
  }
  if (lr == 0) {
#pragma unroll
    for (int v = 0; v < 4; ++v) {
      const int r = m0 + kg * 4 + v;
      if (r < N) { a1[r] = p1[v]; a2[r] = p2[v]; }
    }
  }
}

// ---------------------------------------------------------------------------
// CSR build: histogram + hierarchical scan + two-level bucket sort.
// ---------------------------------------------------------------------------
__global__ void hist_kernel(const int* __restrict__ src, int* __restrict__ deg,
                            int E) {
  int i = blockIdx.x * blockDim.x + threadIdx.x;
  if (i < E) atomicAdd(&deg[src[i]], 1);
}

__global__ __launch_bounds__(1024) void scan1_kernel(
    const int* __restrict__ deg, int* __restrict__ offset,
    int* __restrict__ blocksum, int N) {
  __shared__ int tmp[16];
  const int tid = threadIdx.x;
  const int lane = tid & 63;
  const int wave = tid >> 6;
  int i = blockIdx.x * 1024 + tid;
  int v = (i < N) ? deg[i] : 0;
  int x = v;
#pragma unroll
  for (int d = 1; d < 64; d <<= 1) {
    int y = __shfl_up(x, d, 64);
    if (lane >= d) x += y;
  }
  if (lane == 63) tmp[wave] = x;
  __syncthreads();
  if (tid < 16) {
    int wv = tmp[tid];
#pragma unroll
    for (int d = 1; d < 16; d <<= 1) {
      int y = __shfl_up(wv, d, 16);
      if (tid >= d) wv += y;
    }
    tmp[tid] = wv;
  }
  __syncthreads();
  int waveoff = (wave == 0) ? 0 : tmp[wave - 1];
  if (i < N) offset[i] = waveoff + x - v;
  if (tid == 0) blocksum[blockIdx.x] = tmp[15];
}

__global__ __launch_bounds__(1024) void scan2_kernel(int* __restrict__ blocksum,
                                                     int nb) {
  __shared__ int tmp[16];
  const int tid = threadIdx.x;
  const int lane = tid & 63;
  const int wave = tid >> 6;
  int v = (tid < nb) ? blocksum[tid] : 0;
  int x = v;
#pragma unroll
  for (int d = 1; d < 64; d <<= 1) {
    int y = __shfl_up(x, d, 64);
    if (lane >= d) x += y;
  }
  if (lane == 63) tmp[wave] = x;
  __syncthreads();
  if (tid < 16) {
    int wv = tmp[tid];
#pragma unroll
    for (int d = 1; d < 16; d <<= 1) {
      int y = __shfl_up(wv, d, 16);
      if (tid >= d) wv += y;
    }
    tmp[tid] = wv;
  }
  __syncthreads();
  int waveoff = (wave == 0) ? 0 : tmp[wave - 1];
  if (tid < nb) blocksum[tid] = waveoff + x - v;
}

__global__ void scan3_kernel(int* __restrict__ offset,
                             const int* __restrict__ blocksum, int N) {
  int i = blockIdx.x * blockDim.x + threadIdx.x;
  if (i < N) offset[i] += blocksum[i >> 10];
}

// cursor[b] = offset[128*b]: bucket regions ARE the final CSR ranges.
__global__ void cursor_init_kernel(const int* __restrict__ offset,
                                   int* __restrict__ cursor, int NBK) {
  int b = blockIdx.x * blockDim.x + threadIdx.x;
  if (b < NBK) cursor[b] = offset[b << 7];
}

// L1: scatter edges into their src-bucket's CSR region (order arbitrary).
// Active write window = NBK hot cache lines -> line-dense writes.
__global__ void bucket_scatter_kernel(const int* __restrict__ src,
                                      const int* __restrict__ dst,
                                      int* __restrict__ cursor,
                                      int* __restrict__ ed,
                                      unsigned char* __restrict__ es, int E) {
  int i = blockIdx.x * blockDim.x + threadIdx.x;
  if (i < E) {
    int s = src[i];
    int p = atomicAdd(&cursor[s >> 7], 1);
    ed[p] = dst[i];
    es[p] = (unsigned char)(s & 127);
  }
}

// L2: permute within each bucket to exact CSR positions. One block/bucket.
__global__ __launch_bounds__(256) void bucket_sort_kernel(
    const int* __restrict__ ed, const unsigned char* __restrict__ es,
    const int* __restrict__ offset, int* __restrict__ tsorted, int N, int E) {
  __shared__ int lcnt[128];
  __shared__ int lcur[128];
  const int tid = threadIdx.x;
  const int n0 = blockIdx.x << 7;
  const int base = offset[n0];
  const int bend = (n0 + 128 < N) ? offset[n0 + 128] : E;

  if (tid < 128) lcnt[tid] = 0;
  __syncthreads();
  for (int i = base + tid; i < bend; i += 256)
    atomicAdd(&lcnt[es[i]], 1);
  __syncthreads();
  if (tid == 0) {
    int run = base;
#pragma unroll 8
    for (int j = 0; j < 128; ++j) {
      lcur[j] = run;
      run += lcnt[j];
    }
  }
  __syncthreads();
  for (int i = base + tid; i < bend; i += 256) {
    int p = atomicAdd(&lcur[es[i]], 1);
    tsorted[p] = ed[i];
  }
}

// ---------------------------------------------------------------------------
// Aggregation: one wave per node; 16 lanes x 32B cover one 512B emb row ->
// four items per wave-iteration (q = lane>>4). Item 0 = self-loop.
// ---------------------------------------------------------------------------
__global__ __launch_bounds__(256) void aggregate_kernel(
    const float* __restrict__ emb, const float* __restrict__ a1,
    const float* __restrict__ a2, const int* __restrict__ offset,
    const int* __restrict__ deg, const int* __restrict__ tsorted,
    float* __restrict__ out, int N) {
  int n = (int)((blockIdx.x * (size_t)blockDim.x + threadIdx.x) >> 6);
  int lane = threadIdx.x & 63;
  if (n >= N) return;
  const int q = lane >> 4;
  const int sub = lane & 15;  // covers cols sub*8 .. sub*8+7

  const float as = a1[n];
  const int beg = offset[n];
  const int cnt = deg[n];
  const int items = cnt + 1;  // +1: self loop at item 0
  const int niter = (items + 3) >> 2;

  float4 acc0 = make_float4(0.f, 0.f, 0.f, 0.f);
  float4 acc1 = make_float4(0.f, 0.f, 0.f, 0.f);
  float den = 0.f;

  int idx = q;
  int t = (idx == 0 || idx > cnt) ? n : tsorted[beg + idx - 1];
  float at = a2[t];

  for (int i = 0; i < niter; ++i) {
    const bool valid = (idx < items);
    const float* row = emb + (size_t)t * OUT_DIM + sub * 8;
    const float4 v0 = *(const float4*)row;
    const float4 v1 = *(const float4*)(row + 4);
    const float logit = as + at;
    const int idxn = idx + 4;
    if (i + 1 < niter) {
      int tn = (idxn <= cnt) ? tsorted[beg + idxn - 1] : n;  // idxn >= 4
      t = tn;
      at = a2[tn];
    }
    idx = idxn;
    const float sc = valid ? __expf(logit > 0.f ? logit : SLOPE * logit) : 0.f;
    acc0.x += sc * v0.x; acc0.y += sc * v0.y;
    acc0.z += sc * v0.z; acc0.w += sc * v0.w;
    acc1.x += sc * v1.x; acc1.y += sc * v1.y;
    acc1.z += sc * v1.z; acc1.w += sc * v1.w;
    den += sc;
  }

#pragma unroll
  for (int d = 16; d < 64; d <<= 1) {
    acc0.x += __shfl_xor(acc0.x, d, 64);
    acc0.y += __shfl_xor(acc0.y, d, 64);
    acc0.z += __shfl_xor(acc0.z, d, 64);
    acc0.w += __shfl_xor(acc0.w, d, 64);
    acc1.x += __shfl_xor(acc1.x, d, 64);
    acc1.y += __shfl_xor(acc1.y, d, 64);
    acc1.z += __shfl_xor(acc1.z, d, 64);
    acc1.w += __shfl_xor(acc1.w, d, 64);
    den    += __shfl_xor(den,    d, 64);
  }

  if (q == 0) {
    const float inv = 1.0f / den;
    float* op = out + (size_t)n * OUT_DIM + sub * 8;
    *(float4*)op = make_float4(acc0.x * inv, acc0.y * inv, acc0.z * inv,
                               acc0.w * inv);
    *(float4*)(op + 4) = make_float4(acc1.x * inv, acc1.y * inv, acc1.z * inv,
                                     acc1.w * inv);
  }
}

// ---------------------------------------------------------------------------
extern "C" void kernel_launch(void* const* d_in, const int* in_sizes, int n_in,
                              void* d_out, int out_size, void* d_ws,
                              size_t ws_size, hipStream_t stream) {
  const float* node_feats = (const float*)d_in[0];
  const float* W = (const float*)d_in[1];
  const float* bias = (const float*)d_in[2];
  const float* avec = (const float*)d_in[3];
  const int* src = (const int*)d_in[4];
  const int* dst = (const int*)d_in[5];
  float* out = (float*)d_out;

  const int OUT = in_sizes[2];            // 128
  const int IN = in_sizes[1] / OUT;       // 256
  const int N = in_sizes[0] / IN;         // 100000
  const int E = in_sizes[4];              // 1600000
  const int NB = (N + 1023) / 1024;       // scan blocks (98)
  const int NBK = (N + 127) / 128;        // buckets (782)
  const int WTOT = in_sizes[1];           // 32768

  // Workspace layout (256B-aligned slices). Total ~67 MB.
  char* p = (char*)d_ws;
  auto alloc = [&](size_t bytes) {
    void* r = (void*)p;
    p += (bytes + 255) & ~(size_t)255;
    return r;
  };
  float* emb = (float*)alloc((size_t)N * OUT * sizeof(float));   // 51.2 MB
  float* a1 = (float*)alloc((size_t)N * sizeof(float));
  float* a2 = (float*)alloc((size_t)N * sizeof(float));
  int* deg = (int*)alloc((size_t)N * sizeof(int));
  int* offset = (int*)alloc((size_t)N * sizeof(int));
  int* blocksum = (int*)alloc((size_t)NB * sizeof(int));
  int* cursor = (int*)alloc((size_t)NBK * sizeof(int));
  int* tsorted = (int*)alloc((size_t)E * sizeof(int));           // 6.4 MB
  int* ed = (int*)alloc((size_t)E * sizeof(int));                // 6.4 MB
  unsigned char* es = (unsigned char*)alloc((size_t)E);          // 1.6 MB
  _Float16* Wfp = (_Float16*)alloc((size_t)WTOT * sizeof(_Float16));

  hipMemsetAsync(deg, 0, (size_t)N * sizeof(int), stream);

  convert_w_kernel<<<(WTOT + 255) / 256, 256, 0, stream>>>(W, Wfp, WTOT);
  hist_kernel<<<(E + 255) / 256, 256, 0, stream>>>(src, deg, E);

  gemm_mfma_kernel<<<(N + 63) / 64, 256, 0, stream>>>(
      node_feats, Wfp, bias, avec, emb, a1, a2, N);

  scan1_kernel<<<NB, 1024, 0, stream>>>(deg, offset, blocksum, N);
  scan2_kernel<<<1, 1024, 0, stream>>>(blocksum, NB);
  scan3_kernel<<<(N + 255) / 256, 256, 0, stream>>>(offset, blocksum, N);
  cursor_init_kernel<<<(NBK + 255) / 256, 256, 0, stream>>>(offset, cursor,
                                                            NBK);

  bucket_scatter_kernel<<<(E + 255) / 256, 256, 0, stream>>>(src, dst, cursor,
                                                             ed, es, E);
  bucket_sort_kernel<<<NBK, 256, 0, stream>>>(ed, es, offset, tsorted, N, E);

  aggregate_kernel<<<(N + 3) / 4, 256, 0, stream>>>(emb, a1, a2, offset, deg,
                                                    tsorted, out, N);
}